// Round 2
// baseline (8390.732 us; speedup 1.0000x reference)
//
#include <hip/hip_runtime.h>

#define B_   256
#define T_   168
#define IN_  64
#define H_   512
#define G_   2048
#define HOR_ 24

typedef unsigned short u16;
typedef __bf16 bf16x8 __attribute__((ext_vector_type(8)));
typedef float  f32x4  __attribute__((ext_vector_type(4)));

__device__ __forceinline__ u16 f2bf(float f) {
  unsigned u = __float_as_uint(f);
  u += 0x7fffu + ((u >> 16) & 1u);   // round-to-nearest-even
  return (u16)(u >> 16);
}
__device__ __forceinline__ float bf2f(u16 h) {
  return __uint_as_float(((unsigned)h) << 16);
}

// ---------------- split fp32 -> bf16 hi + bf16 lo ----------------
__global__ __launch_bounds__(256) void split_kernel(const float* __restrict__ src,
                                                    u16* __restrict__ hi,
                                                    u16* __restrict__ lo, int n4) {
  int i = blockIdx.x * 256 + threadIdx.x;
  if (i >= n4) return;
  float4 v = ((const float4*)src)[i];
  ushort4 h, l;
  h.x = f2bf(v.x); l.x = f2bf(v.x - bf2f(h.x));
  h.y = f2bf(v.y); l.y = f2bf(v.y - bf2f(h.y));
  h.z = f2bf(v.z); l.z = f2bf(v.z - bf2f(h.z));
  h.w = f2bf(v.w); l.w = f2bf(v.w - bf2f(h.w));
  ((ushort4*)hi)[i] = h;
  ((ushort4*)lo)[i] = l;
}

// ---------------- one LSTM layer-step (possibly 2 independent jobs) ----------------
// Gates GEMM: gates[256,2048] = A1[256,K1] @ W1^T + A2[256,512] @ W2^T (+ bias + x-outer)
// split-bf16: each operand has hi/lo; 3 MFMAs per 16x16x32 chunk.
// Grid per job: 256 blocks = 8 m-tiles(32 rows) x 32 hcol-tiles(16 cols).
// Block: 4 waves; wave = (mb in 0..1) x (strip-pair sp in 0..1); strips = gates i,f,g,o.
struct StepJob {
  const u16* A1h; const u16* A1l; const u16* W1h; const u16* W1l;
  const u16* A2h; const u16* A2l; const u16* W2h; const u16* W2l;
  const float* bias; const float* xvec; const float* xscal;
  float* c; u16* Hh; u16* Hl;
  int a1Stride; int K1;
};
struct StepParams { StepJob job[2]; };

__global__ __launch_bounds__(256) void lstm_step_kernel(StepParams p) {
  const StepJob J = p.job[blockIdx.x >> 8];
  const int bx   = blockIdx.x & 255;
  const int hc   = bx & 31;          // hcol tile * 16
  const int mt   = bx >> 5;          // m tile * 32
  const int lane = threadIdx.x & 63;
  const int wave = threadIdx.x >> 6;
  const int mb   = wave & 1;         // 16-row block within 32-row tile
  const int sp   = wave >> 1;        // strip pair: 0 -> (i,f), 1 -> (g,o)
  const int l16  = lane & 15;
  const int lk   = lane >> 4;        // k-group 0..3

  const int arow = mt * 32 + mb * 16 + l16;
  const int hcb  = hc * 16;
  const int s0   = sp * 2;

  f32x4 acc0 = {0.f, 0.f, 0.f, 0.f};
  f32x4 acc1 = {0.f, 0.f, 0.f, 0.f};

  #pragma unroll 1
  for (int seg = 0; seg < 2; ++seg) {
    const u16 *Ah, *Al, *Wh, *Wl; int K, astr;
    if (seg == 0) {
      K = J.K1; if (K == 0) continue;
      Ah = J.A1h; Al = J.A1l; Wh = J.W1h; Wl = J.W1l; astr = J.a1Stride;
    } else {
      Ah = J.A2h; Al = J.A2l; Wh = J.W2h; Wl = J.W2l; K = 512; astr = 512;
    }
    const u16* aph = Ah + (size_t)arow * astr + lk * 8;
    const u16* apl = Al + (size_t)arow * astr + lk * 8;
    const size_t w0 = (size_t)(s0 * 512 + hcb + l16) * K + lk * 8;
    const size_t w1 = (size_t)((s0 + 1) * 512 + hcb + l16) * K + lk * 8;
    const u16* bh0 = Wh + w0; const u16* bl0 = Wl + w0;
    const u16* bh1 = Wh + w1; const u16* bl1 = Wl + w1;
    for (int k = 0; k < K; k += 32) {
      bf16x8 ah  = *(const bf16x8*)(aph + k);
      bf16x8 al  = *(const bf16x8*)(apl + k);
      bf16x8 p0h = *(const bf16x8*)(bh0 + k);
      bf16x8 p0l = *(const bf16x8*)(bl0 + k);
      bf16x8 p1h = *(const bf16x8*)(bh1 + k);
      bf16x8 p1l = *(const bf16x8*)(bl1 + k);
      acc0 = __builtin_amdgcn_mfma_f32_16x16x32_bf16(ah, p0h, acc0, 0, 0, 0);
      acc1 = __builtin_amdgcn_mfma_f32_16x16x32_bf16(ah, p1h, acc1, 0, 0, 0);
      acc0 = __builtin_amdgcn_mfma_f32_16x16x32_bf16(ah, p0l, acc0, 0, 0, 0);
      acc1 = __builtin_amdgcn_mfma_f32_16x16x32_bf16(ah, p1l, acc1, 0, 0, 0);
      acc0 = __builtin_amdgcn_mfma_f32_16x16x32_bf16(al, p0h, acc0, 0, 0, 0);
      acc1 = __builtin_amdgcn_mfma_f32_16x16x32_bf16(al, p1h, acc1, 0, 0, 0);
    }
  }

  // exchange strips g,o (sp==1 waves) -> sp==0 waves do the pointwise
  __shared__ float xch[2][16][16][2];
  if (sp == 1) {
    #pragma unroll
    for (int r = 0; r < 4; ++r) {
      xch[mb][lk * 4 + r][l16][0] = acc0[r];   // gate g
      xch[mb][lk * 4 + r][l16][1] = acc1[r];   // gate o
    }
  }
  __syncthreads();
  if (sp == 0) {
    const int hcol = hcb + l16;
    const float bi = J.bias[hcol];
    const float bf = J.bias[512 + hcol];
    const float bg = J.bias[1024 + hcol];
    const float bo = J.bias[1536 + hcol];
    float xvi = 0.f, xvf = 0.f, xvg = 0.f, xvo = 0.f;
    const bool hasx = (J.xvec != nullptr);
    if (hasx) {
      xvi = J.xvec[hcol];        xvf = J.xvec[512 + hcol];
      xvg = J.xvec[1024 + hcol]; xvo = J.xvec[1536 + hcol];
    }
    #pragma unroll
    for (int r = 0; r < 4; ++r) {
      const int row = mt * 32 + mb * 16 + lk * 4 + r;
      const size_t idx = (size_t)row * 512 + hcol;
      float xs = hasx ? J.xscal[row] : 0.f;
      float gi = acc0[r] + bi + xvi * xs;
      float gf = acc1[r] + bf + xvf * xs;
      float gg = xch[mb][lk * 4 + r][l16][0] + bg + xvg * xs;
      float go = xch[mb][lk * 4 + r][l16][1] + bo + xvo * xs;
      float si = 1.f / (1.f + expf(-gi));
      float sf = 1.f / (1.f + expf(-gf));
      float so = 1.f / (1.f + expf(-go));
      float cn = sf * J.c[idx] + si * tanhf(gg);
      float hn = so * tanhf(cn);
      J.c[idx] = cn;
      u16 hh = f2bf(hn);
      J.Hh[idx] = hh;
      J.Hl[idx] = f2bf(hn - bf2f(hh));
    }
  }
}

// ---------------- fc: out[b] = h1[b,:] . fcW + fcb ----------------
__global__ __launch_bounds__(256) void fc_kernel(const u16* __restrict__ Hh,
                                                 const u16* __restrict__ Hl,
                                                 const float* __restrict__ fcW,
                                                 const float* __restrict__ fcb,
                                                 float* __restrict__ pout,
                                                 float* __restrict__ dout, int step) {
  int tid = threadIdx.x;
  int r = blockIdx.x * 16 + (tid >> 4);
  int c = tid & 15;
  float s = 0.f;
  int k0 = c * 32;
  for (int k = k0; k < k0 + 32; ++k) {
    float h = bf2f(Hh[(size_t)r * 512 + k]) + bf2f(Hl[(size_t)r * 512 + k]);
    s += h * fcW[k];
  }
  for (int off = 8; off; off >>= 1) s += __shfl_down(s, off, 16);
  if (c == 0) {
    float o = s + fcb[0];
    pout[r] = o;
    dout[(size_t)r * HOR_ + step] = o;
  }
}

// ---------------- host ----------------
extern "C" void kernel_launch(void* const* d_in, const int* in_sizes, int n_in,
                              void* d_out, int out_size, void* d_ws, size_t ws_size,
                              hipStream_t stream) {
  const float* x   = (const float*)d_in[0];
  const float* eW0 = (const float*)d_in[2];
  const float* eU0 = (const float*)d_in[3];
  const float* eb0 = (const float*)d_in[4];
  const float* eW1 = (const float*)d_in[5];
  const float* eU1 = (const float*)d_in[6];
  const float* eb1 = (const float*)d_in[7];
  const float* dW0 = (const float*)d_in[8];
  const float* dU0 = (const float*)d_in[9];
  const float* db0 = (const float*)d_in[10];
  const float* dW1 = (const float*)d_in[11];
  const float* dU1 = (const float*)d_in[12];
  const float* db1 = (const float*)d_in[13];
  const float* fcW = (const float*)d_in[14];
  const float* fcb = (const float*)d_in[15];
  float* dout = (float*)d_out;

  char* base = (char*)d_ws;
  size_t off = 0;
  auto alloc = [&](size_t bytes) -> char* {
    char* p = base + off;
    off = (off + bytes + 255) & ~(size_t)255;
    return p;
  };

  const size_t nx = (size_t)B_ * T_ * IN_;
  u16* xhi = (u16*)alloc(nx * 2);
  u16* xlo = (u16*)alloc(nx * 2);
  const size_t nW0 = (size_t)G_ * IN_;   // 131072
  const size_t nWH = (size_t)G_ * H_;    // 1048576
  u16 *eW0h = (u16*)alloc(nW0 * 2), *eW0l = (u16*)alloc(nW0 * 2);
  u16 *eU0h = (u16*)alloc(nWH * 2), *eU0l = (u16*)alloc(nWH * 2);
  u16 *eW1h = (u16*)alloc(nWH * 2), *eW1l = (u16*)alloc(nWH * 2);
  u16 *eU1h = (u16*)alloc(nWH * 2), *eU1l = (u16*)alloc(nWH * 2);
  u16 *dU0h = (u16*)alloc(nWH * 2), *dU0l = (u16*)alloc(nWH * 2);
  u16 *dW1h = (u16*)alloc(nWH * 2), *dW1l = (u16*)alloc(nWH * 2);
  u16 *dU1h = (u16*)alloc(nWH * 2), *dU1l = (u16*)alloc(nWH * 2);

  // zero-initialized state region
  char* zbase = base + off;
  const size_t nh = (size_t)B_ * H_;
  u16 *h0h[2], *h0l[2], *h1h[2], *h1l[2];
  for (int i = 0; i < 2; ++i) { h0h[i] = (u16*)alloc(nh * 2); h0l[i] = (u16*)alloc(nh * 2); }
  for (int i = 0; i < 2; ++i) { h1h[i] = (u16*)alloc(nh * 2); h1l[i] = (u16*)alloc(nh * 2); }
  float* c0   = (float*)alloc(nh * 4);
  float* c1   = (float*)alloc(nh * 4);
  float* pout = (float*)alloc(B_ * 4);
  float* zb   = (float*)alloc(B_ * 4);
  size_t zbytes = (size_t)((base + off) - zbase);
  (void)ws_size; (void)in_sizes; (void)n_in; (void)out_size;

  hipMemsetAsync(zbase, 0, zbytes, stream);

  auto split = [&](const float* s, u16* h, u16* l, size_t n) {
    int n4 = (int)(n / 4);
    split_kernel<<<dim3((n4 + 255) / 256), dim3(256), 0, stream>>>(s, h, l, n4);
  };
  split(x, xhi, xlo, nx);
  split(eW0, eW0h, eW0l, nW0);
  split(eU0, eU0h, eU0l, nWH);
  split(eW1, eW1h, eW1l, nWH);
  split(eU1, eU1h, eU1l, nWH);
  split(dU0, dU0h, dU0l, nWH);
  split(dW1, dW1h, dW1l, nWH);
  split(dU1, dU1h, dU1l, nWH);

  int c0i = 0, c1i = 0;

  // ---------- encoder: fused (layer0 step t) + (layer1 step t-1) ----------
  for (int t = 0; t <= T_; ++t) {
    StepParams P; int nj = 0;
    if (t < T_) {
      StepJob j{};
      j.A1h = xhi + (size_t)t * IN_; j.A1l = xlo + (size_t)t * IN_;
      j.a1Stride = T_ * IN_; j.K1 = IN_;
      j.W1h = eW0h; j.W1l = eW0l;
      j.A2h = h0h[c0i]; j.A2l = h0l[c0i];
      j.W2h = eU0h; j.W2l = eU0l;
      j.bias = eb0; j.xvec = nullptr; j.xscal = nullptr;
      j.c = c0; j.Hh = h0h[1 - c0i]; j.Hl = h0l[1 - c0i];
      P.job[nj++] = j;
    }
    if (t >= 1) {
      StepJob j{};
      j.A1h = h0h[c0i]; j.A1l = h0l[c0i]; j.a1Stride = 512; j.K1 = 512;
      j.W1h = eW1h; j.W1l = eW1l;
      j.A2h = h1h[c1i]; j.A2l = h1l[c1i];
      j.W2h = eU1h; j.W2l = eU1l;
      j.bias = eb1; j.xvec = nullptr; j.xscal = nullptr;
      j.c = c1; j.Hh = h1h[1 - c1i]; j.Hl = h1l[1 - c1i];
      P.job[nj++] = j;
    }
    if (nj == 1) P.job[1] = P.job[0];
    lstm_step_kernel<<<dim3(nj * 256), dim3(256), 0, stream>>>(P);
    if (t < T_) c0i ^= 1;
    if (t >= 1) c1i ^= 1;
  }

  // ---------- decoder: autoregressive ----------
  for (int s = 0; s < HOR_; ++s) {
    {
      StepJob j{};
      j.A1h = nullptr; j.A1l = nullptr; j.a1Stride = 0; j.K1 = 0;
      j.W1h = nullptr; j.W1l = nullptr;
      j.A2h = h0h[c0i]; j.A2l = h0l[c0i];
      j.W2h = dU0h; j.W2l = dU0l;
      j.bias = db0; j.xvec = dW0; j.xscal = (s == 0 ? zb : pout);
      j.c = c0; j.Hh = h0h[1 - c0i]; j.Hl = h0l[1 - c0i];
      StepParams P; P.job[0] = j; P.job[1] = j;
      lstm_step_kernel<<<dim3(256), dim3(256), 0, stream>>>(P);
      c0i ^= 1;
    }
    {
      StepJob j{};
      j.A1h = h0h[c0i]; j.A1l = h0l[c0i]; j.a1Stride = 512; j.K1 = 512;
      j.W1h = dW1h; j.W1l = dW1l;
      j.A2h = h1h[c1i]; j.A2l = h1l[c1i];
      j.W2h = dU1h; j.W2l = dU1l;
      j.bias = db1; j.xvec = nullptr; j.xscal = nullptr;
      j.c = c1; j.Hh = h1h[1 - c1i]; j.Hl = h1l[1 - c1i];
      StepParams P; P.job[0] = j; P.job[1] = j;
      lstm_step_kernel<<<dim3(256), dim3(256), 0, stream>>>(P);
      c1i ^= 1;
    }
    fc_kernel<<<dim3(16), dim3(256), 0, stream>>>(h1h[c1i], h1l[c1i], fcW, fcb, pout, dout, s);
  }
}